// Round 7
// baseline (4529.526 us; speedup 1.0000x reference)
//
#include <hip/hip_runtime.h>

// LightGCN: out = (x0 + A x0 + A^2 x0 + A^3 x0) / 4, COO 4M nnz, N=300k, D=64.
// R5: bf16 activations; R6: SGPR edge records; R7: bucket build pipeline;
// R8: fp32 acc deleted, mean fused into final layer.
// R9/R10: MLP depth 4->16: no effect. R11: quad-edge gathers -> compiler
//      spilled the per-lane record selects to scratch (WRITE 2.7GB, 822us).
//      REVERTED. Conclusion so far: spmm is bound by a random-line touch
//      rate (~26G lines/s device-wide), invariant to FETCH and SW MLP.
// R12: LDS-accumulator group-SpMM. Block = 256-row group, 64KB fp32 acc in
//      LDS; 4 waves split the group's edges; per edge: SGPR record ->
//      128B gather -> ds_add_f32. Edges within a group need NO row order,
//      so k_bucketB + packed + rowptr are DELETED (bucketA bins straight
//      into 1172 groups). Also the structural prerequisite for col-sliced
//      gathers (L2-resident slices) next. Occupancy probe: 2 blocks/CU --
//      if spmm holds ~160us the rate theory stands.

#define NUSERS 200000
#define NITEMS 100000
#define NNODES 300000
#define DIM 64
#define NNZ_CNT 4000000

#define GSH 8                                   // 256 rows per group
#define GROWS (1 << GSH)
#define NG ((NNODES + GROWS - 1) >> GSH)        // 1172 groups
#define EPB 8192                                // edges per block (hist/A)

// ---------------- bf16 helpers (RNE) ----------------

__device__ __forceinline__ unsigned short f32_to_bf16(float f) {
    unsigned u = __float_as_uint(f);
    u += 0x7FFFu + ((u >> 16) & 1u);
    return (unsigned short)(u >> 16);
}
__device__ __forceinline__ float bf16_to_f32(unsigned short h) {
    return __uint_as_float(((unsigned)h) << 16);
}

// ---------------- group totals: LDS hist, few global atomics ----------------

__global__ void __launch_bounds__(256) k_bhist(const int* __restrict__ rows,
                                               int* __restrict__ bcnt) {
    __shared__ int hist[NG];
    int t = threadIdx.x;
    int e0 = blockIdx.x * EPB;
    for (int i = t; i < NG; i += 256) hist[i] = 0;
    __syncthreads();
    for (int k = 0; k < EPB / 256; ++k) {
        int e = e0 + k * 256 + t;
        if (e < NNZ_CNT) atomicAdd(&hist[rows[e] >> GSH], 1);
    }
    __syncthreads();
    for (int i = t; i < NG; i += 256) {
        int h = hist[i];
        if (h) atomicAdd(&bcnt[i], h);
    }
}

// 1 block, 1024 threads, 2 elems/thread: exclusive scan of group counts.
__global__ void __launch_bounds__(1024) k_bscan(const int* __restrict__ bcnt,
                                                int* __restrict__ bbase,
                                                int* __restrict__ gcur) {
    int t = threadIdx.x;
    int i0 = 2 * t, i1 = 2 * t + 1;
    int a = (i0 < NG) ? bcnt[i0] : 0;
    int b = (i1 < NG) ? bcnt[i1] : 0;
    int s = a + b;
    __shared__ int lds[1024];
    lds[t] = s; __syncthreads();
    for (int d = 1; d < 1024; d <<= 1) {
        int cur = lds[t];
        int add = (t >= d) ? lds[t - d] : 0;
        __syncthreads();
        lds[t] = cur + add;
        __syncthreads();
    }
    int excl = lds[t] - s;
    if (i0 < NG) { bbase[i0] = excl;     gcur[i0] = excl; }
    if (i1 < NG) { bbase[i1] = excl + a; gcur[i1] = excl + a; }
    if (t == 1023) bbase[NG] = lds[1023];   // == NNZ
}

// ---------------- bucketA: COO -> staged (group-binned) ----------------

__global__ void __launch_bounds__(256) k_bucketA(
        const int* __restrict__ rows, const int* __restrict__ cols,
        const float* __restrict__ vals, int* __restrict__ gcursor,
        int2* __restrict__ staged) {
    __shared__ int hist[NG];
    __shared__ int lbase[NG];
    __shared__ int lcur[NG];
    int t = threadIdx.x;
    int e0 = blockIdx.x * EPB;
    for (int i = t; i < NG; i += 256) { hist[i] = 0; lcur[i] = 0; }
    __syncthreads();
    // pass 1: local histogram
    for (int k = 0; k < EPB / 256; ++k) {
        int e = e0 + k * 256 + t;
        if (e < NNZ_CNT) atomicAdd(&hist[rows[e] >> GSH], 1);
    }
    __syncthreads();
    // reserve contiguous ranges per group
    for (int i = t; i < NG; i += 256) {
        int h = hist[i];
        lbase[i] = h ? atomicAdd(&gcursor[i], h) : 0;
    }
    __syncthreads();
    // pass 2: place edges (rel_row[8] | col[19])
    for (int k = 0; k < EPB / 256; ++k) {
        int e = e0 + k * 256 + t;
        if (e >= NNZ_CNT) continue;
        int r = rows[e];
        int g = r >> GSH;
        int p = lbase[g] + atomicAdd(&lcur[g], 1);
        int2 rec;
        rec.x = ((r & (GROWS - 1)) << 19) | cols[e];
        rec.y = __float_as_int(vals[e]);
        staged[p] = rec;
    }
}

// ---------------- x0 -> bf16 ----------------

__global__ void k_init0(const float* __restrict__ ue, const float* __restrict__ ie,
                        unsigned short* __restrict__ xb0) {
    int i = blockIdx.x * blockDim.x + threadIdx.x;      // float4 index
    const int total = NNODES * DIM / 4;
    if (i >= total) return;
    const int userEnd = NUSERS * DIM / 4;
    float4 v = (i < userEnd) ? ((const float4*)ue)[i]
                             : ((const float4*)ie)[i - userEnd];
    ushort4 h;
    h.x = f32_to_bf16(v.x); h.y = f32_to_bf16(v.y);
    h.z = f32_to_bf16(v.z); h.w = f32_to_bf16(v.w);
    ((ushort4*)xb0)[i] = h;
}

// ---------------- group SpMM: LDS fp32 acc, SGPR records, bf16 gathers ------

// Block = one 256-row group, acc[256][64] fp32 in LDS (64KB). 4 waves split
// the group's edge range; per edge: wave-uniform record (s_load block of 16,
// staged padded so no clamp), one 128B row gather, ds_add_f32 into
// acc[rel][lane]. Tail edges get v=0 (uniform select); their gather reads a
// real neighbor record's row (or pad row 0) -> valid address, free prefetch.
// FINAL=0: y = bf16(acc)   FINAL=1: out = (x0 + x1 + x2 + acc) * 0.25
template <int FINAL>
__global__ void __launch_bounds__(256) k_spmm(
        const int* __restrict__ bbase, const int2* __restrict__ staged,
        const unsigned short* __restrict__ xin,
        unsigned short* __restrict__ y,
        const unsigned short* __restrict__ xprev,
        const float* __restrict__ ue, const float* __restrict__ ie,
        float* __restrict__ out) {
    __shared__ float acc[GROWS * DIM];                 // 64 KB
    int g    = blockIdx.x;
    int t    = threadIdx.x;
    int lane = t & 63;
    int w    = t >> 6;                                 // wave id 0..3
    int r0   = g << GSH;

    float4* az = (float4*)acc;
    for (int i = t; i < GROWS * DIM / 4; i += 256) az[i] = make_float4(0.f, 0.f, 0.f, 0.f);
    __syncthreads();

    int gstart = bbase[g];
    int gend   = bbase[g + 1];
    int n      = gend - gstart;
    int q0 = __builtin_amdgcn_readfirstlane(gstart + ((n * w) >> 2));
    int q1 = __builtin_amdgcn_readfirstlane(gstart + ((n * (w + 1)) >> 2));

    const unsigned short* __restrict__ xl = xin + lane;
    for (int base = q0; base < q1; base += 16) {
        int2 e[16];
        #pragma unroll
        for (int j = 0; j < 16; ++j) e[j] = staged[base + j];   // contiguous s_load block
        #pragma unroll
        for (int j = 0; j < 16; ++j) {
            int   cx  = e[j].x;
            float v   = (base + j < q1) ? __int_as_float(e[j].y) : 0.0f;
            int   col = cx & 0x7FFFF;
            int   rel = ((unsigned)cx) >> 19;
            float gv  = bf16_to_f32(xl[(size_t)col << 6]);
            atomicAdd(&acc[(rel << 6) + lane], v * gv);
        }
    }
    __syncthreads();

    // epilogue: acc viewed as float4[u], u = rel*16 + quad
    int nrows = min(GROWS, NNODES - r0);
    int units = nrows * 16;
    for (int u = t; u < units; u += 256) {
        float4 a = ((const float4*)acc)[u];
        int row = r0 + (u >> 4);
        size_t ro = (size_t)r0 * 16 + u;               // float4/ushort4 units
        if (FINAL) {
            float4 x0 = (row < NUSERS) ? ((const float4*)ue)[ro]
                                       : ((const float4*)ie)[ro - (size_t)NUSERS * 16];
            ushort4 h1 = ((const ushort4*)xprev)[ro];
            ushort4 h2 = ((const ushort4*)xin)[ro];
            float4 r;
            r.x = (x0.x + bf16_to_f32(h1.x) + bf16_to_f32(h2.x) + a.x) * 0.25f;
            r.y = (x0.y + bf16_to_f32(h1.y) + bf16_to_f32(h2.y) + a.y) * 0.25f;
            r.z = (x0.z + bf16_to_f32(h1.z) + bf16_to_f32(h2.z) + a.z) * 0.25f;
            r.w = (x0.w + bf16_to_f32(h1.w) + bf16_to_f32(h2.w) + a.w) * 0.25f;
            ((float4*)out)[ro] = r;
        } else {
            ushort4 h;
            h.x = f32_to_bf16(a.x); h.y = f32_to_bf16(a.y);
            h.z = f32_to_bf16(a.z); h.w = f32_to_bf16(a.w);
            ((ushort4*)y)[ro] = h;
        }
    }
}

// ---------------- launch ----------------

extern "C" void kernel_launch(void* const* d_in, const int* in_sizes, int n_in,
                              void* d_out, int out_size, void* d_ws, size_t ws_size,
                              hipStream_t stream) {
    const float* ue   = (const float*)d_in[0];
    const float* ie   = (const float*)d_in[1];
    const int*   rows = (const int*)d_in[2];
    const int*   cols = (const int*)d_in[3];
    const float* vals = (const float*)d_in[4];
    float* out = (float*)d_out;

    const size_t embN = (size_t)NNODES * DIM;            // 19.2M elements
    char* p = (char*)d_ws;
    unsigned short* xb0 = (unsigned short*)p;  p += embN * 2;                 // 38.4 MB
    unsigned short* xb1 = (unsigned short*)p;  p += embN * 2;                 // 38.4 MB
    unsigned short* xb2 = (unsigned short*)p;  p += embN * 2;                 // 38.4 MB
    int*   bcnt   = (int*)p;              p += 2048 * 4;
    int*   bbase  = (int*)p;              p += 2048 * 4;
    int*   gcur   = (int*)p;              p += 2048 * 4;
    int2*  staged = (int2*)p;             p += (size_t)(NNZ_CNT + 16) * 8;    // 32 MB + pad

    const int edge_hblocks = (NNZ_CNT + EPB - 1) / EPB;   // 489
    const int vec_blocks = (NNODES * DIM / 4 + 255) / 256;

    // --- group totals + bases ---
    hipMemsetAsync(bcnt, 0, 2048 * 4, stream);
    hipMemsetAsync(staged + NNZ_CNT, 0, 16 * sizeof(int2), stream);  // gather pad
    k_bhist<<<edge_hblocks, 256, 0, stream>>>(rows, bcnt);
    k_bscan<<<1, 1024, 0, stream>>>(bcnt, bbase, gcur);

    // --- bucket sort: COO -> staged (group-binned; NO per-row sort needed) ---
    k_bucketA<<<edge_hblocks, 256, 0, stream>>>(rows, cols, vals, gcur, staged);

    // --- x0 -> bf16 ---
    k_init0<<<vec_blocks, 256, 0, stream>>>(ue, ie, xb0);

    // --- 3 layers; mean fused into the last (reads x0 fp32 + x1,x2 bf16) ---
    k_spmm<0><<<NG, 256, 0, stream>>>(bbase, staged, xb0, xb1,
                                      (const unsigned short*)nullptr, ue, ie, (float*)nullptr);
    k_spmm<0><<<NG, 256, 0, stream>>>(bbase, staged, xb1, xb2,
                                      (const unsigned short*)nullptr, ue, ie, (float*)nullptr);
    k_spmm<1><<<NG, 256, 0, stream>>>(bbase, staged, xb2, (unsigned short*)nullptr,
                                      xb1, ue, ie, out);
}

// Round 8
// 756.346 us; speedup vs baseline: 5.9887x; 5.9887x over previous
//
#include <hip/hip_runtime.h>

// LightGCN: out = (x0 + A x0 + A^2 x0 + A^3 x0) / 4, COO 4M nnz, N=300k, D=64.
// R5: bf16 activations; R6: SGPR edge records; R7: bucket build pipeline;
// R8: fp32 acc deleted, mean fused into final layer (722us, spmm 160).
// R9/R10: MLP 4->16 deep: NO effect. R11: quad-edge: scratch spill, revert.
// R12: LDS-atomic group accumulation: serialized RMW chain (1425us), revert.
// Conclusion: spmm sits at the random-128B-line HBM ceiling; FETCH ~= 8x
//   table size => every XCD re-fetches the gather table from HBM, L3 does
//   NOT retain it. Hypothesis: the per-dispatch streaming traffic (records,
//   y writes, epilogue streams) evicts gather lines from L2/L3.
// R13: restore R8 structure + NON-TEMPORAL on every streaming access
//   (y stores, final-layer x0/x1/x2 loads + out stores, bucketB's last-use
//   staged reads, init0 input reads) so only gather lines occupy cache.
//   Plus int4-vectorized edge reads in bhist/bucketA. If spmm FETCH/dur
//   don't move, the churn theory is dead and spmm is at its roofline.

#define NUSERS 200000
#define NITEMS 100000
#define NNODES 300000
#define DIM 64
#define NNZ_CNT 4000000

#define BSHIFT 10
#define BROWS  (1 << BSHIFT)                               // 1024 rows per bucket
#define NB     ((NNODES + BROWS - 1) >> BSHIFT)            // 293 buckets
#define EPB    8192                                        // edges per block (hist/A)

typedef int   v2i __attribute__((ext_vector_type(2)));

// ---------------- bf16 helpers (RNE) ----------------

__device__ __forceinline__ unsigned short f32_to_bf16(float f) {
    unsigned u = __float_as_uint(f);
    u += 0x7FFFu + ((u >> 16) & 1u);
    return (unsigned short)(u >> 16);
}
__device__ __forceinline__ float bf16_to_f32(unsigned short h) {
    return __uint_as_float(((unsigned)h) << 16);
}

// ---------------- bucket totals: LDS hist, few global atomics ----------------

__global__ void __launch_bounds__(256) k_bhist(const int* __restrict__ rows,
                                               int* __restrict__ bcnt) {
    __shared__ int hist[NB];
    int t = threadIdx.x;
    int e0 = blockIdx.x * EPB;
    for (int i = t; i < NB; i += 256) hist[i] = 0;
    __syncthreads();
    for (int k = 0; k < EPB / 1024; ++k) {               // int4: 4 edges/thread/iter
        int e = e0 + (k * 256 + t) * 4;
        if (e + 4 <= NNZ_CNT) {
            int4 r4 = ((const int4*)rows)[e >> 2];
            atomicAdd(&hist[r4.x >> BSHIFT], 1);
            atomicAdd(&hist[r4.y >> BSHIFT], 1);
            atomicAdd(&hist[r4.z >> BSHIFT], 1);
            atomicAdd(&hist[r4.w >> BSHIFT], 1);
        } else {
            for (int j = 0; j < 4; ++j)
                if (e + j < NNZ_CNT) atomicAdd(&hist[rows[e + j] >> BSHIFT], 1);
        }
    }
    __syncthreads();
    for (int i = t; i < NB; i += 256) {
        int h = hist[i];
        if (h) atomicAdd(&bcnt[i], h);
    }
}

// 1 block, 512 threads: exclusive scan of bucket counts -> bases + cursors.
__global__ void k_bscan(const int* __restrict__ bcnt, int* __restrict__ bbase,
                        int* __restrict__ gcur) {
    int t = threadIdx.x;
    int v = (t < NB) ? bcnt[t] : 0;
    __shared__ int lds[512];
    lds[t] = v; __syncthreads();
    for (int d = 1; d < 512; d <<= 1) {
        int cur = lds[t];
        int add = (t >= d) ? lds[t - d] : 0;
        __syncthreads();
        lds[t] = cur + add;
        __syncthreads();
    }
    if (t < NB) {
        int e = lds[t] - v;          // exclusive
        bbase[t] = e;
        gcur[t]  = e;
    }
    if (t == 511) bbase[NB] = lds[511];   // == NNZ
}

// ---------------- Phase A: bucket staging (LDS-binned) ----------------

__global__ void __launch_bounds__(256) k_bucketA(
        const int* __restrict__ rows, const int* __restrict__ cols,
        const float* __restrict__ vals, int* __restrict__ gcursor,
        int2* __restrict__ staged) {
    __shared__ int hist[NB];
    __shared__ int lbase[NB];
    __shared__ int lcur[NB];
    int t = threadIdx.x;
    int e0 = blockIdx.x * EPB;
    for (int i = t; i < NB; i += 256) { hist[i] = 0; lcur[i] = 0; }
    __syncthreads();
    // pass 1: local histogram (int4)
    for (int k = 0; k < EPB / 1024; ++k) {
        int e = e0 + (k * 256 + t) * 4;
        if (e + 4 <= NNZ_CNT) {
            int4 r4 = ((const int4*)rows)[e >> 2];
            atomicAdd(&hist[r4.x >> BSHIFT], 1);
            atomicAdd(&hist[r4.y >> BSHIFT], 1);
            atomicAdd(&hist[r4.z >> BSHIFT], 1);
            atomicAdd(&hist[r4.w >> BSHIFT], 1);
        } else {
            for (int j = 0; j < 4; ++j)
                if (e + j < NNZ_CNT) atomicAdd(&hist[rows[e + j] >> BSHIFT], 1);
        }
    }
    __syncthreads();
    // reserve contiguous ranges per bucket
    for (int i = t; i < NB; i += 256) {
        int h = hist[i];
        lbase[i] = h ? atomicAdd(&gcursor[i], h) : 0;
    }
    __syncthreads();
    // pass 2: place edges (int4 loads, 4 scatter stores)
    for (int k = 0; k < EPB / 1024; ++k) {
        int e = e0 + (k * 256 + t) * 4;
        if (e + 4 <= NNZ_CNT) {
            int4   r4 = ((const int4*)rows)[e >> 2];
            int4   c4 = ((const int4*)cols)[e >> 2];
            float4 v4 = ((const float4*)vals)[e >> 2];
            int rr[4] = {r4.x, r4.y, r4.z, r4.w};
            int cc[4] = {c4.x, c4.y, c4.z, c4.w};
            float vv[4] = {v4.x, v4.y, v4.z, v4.w};
            #pragma unroll
            for (int j = 0; j < 4; ++j) {
                int r = rr[j];
                int b = r >> BSHIFT;
                int p = lbase[b] + atomicAdd(&lcur[b], 1);
                int2 rec;
                rec.x = ((r & (BROWS - 1)) << 19) | cc[j];   // rel[10] | col[19]
                rec.y = __float_as_int(vv[j]);
                staged[p] = rec;
            }
        } else {
            for (int j = 0; j < 4; ++j) {
                if (e + j >= NNZ_CNT) continue;
                int r = rows[e + j];
                int b = r >> BSHIFT;
                int p = lbase[b] + atomicAdd(&lcur[b], 1);
                int2 rec;
                rec.x = ((r & (BROWS - 1)) << 19) | cols[e + j];
                rec.y = __float_as_int(vals[e + j]);
                staged[p] = rec;
            }
        }
    }
}

// ---------------- Phase B: per-bucket count + scan + row sort ----------------

__global__ void __launch_bounds__(1024) k_bucketB(
        const int* __restrict__ bbase, const int2* __restrict__ staged,
        int2* __restrict__ packed, int* __restrict__ rowptr) {
    __shared__ int rcnt[BROWS];
    __shared__ int cur[BROWS];
    int b = blockIdx.x;
    int t = threadIdx.x;
    int r0 = b << BSHIFT;
    int r1 = min(r0 + BROWS, NNODES);
    int nrows = r1 - r0;
    rcnt[t] = 0;
    __syncthreads();
    int start = bbase[b];
    int end   = bbase[b + 1];
    // pass 1: per-row counts (nt read of records -- last-use data)
    for (int idx = start + t; idx < end; idx += 1024) {
        v2i rec = __builtin_nontemporal_load((const v2i*)&staged[idx]);
        atomicAdd(&rcnt[((unsigned)rec.x) >> 19], 1);
    }
    __syncthreads();
    int v = rcnt[t];
    // in-place inclusive scan (Hillis-Steele)
    for (int d = 1; d < 1024; d <<= 1) {
        int c = rcnt[t];
        int a = (t >= d) ? rcnt[t - d] : 0;
        __syncthreads();
        rcnt[t] = c + a;
        __syncthreads();
    }
    int excl = rcnt[t] - v;
    cur[t] = start + excl;
    if (t < nrows) rowptr[r0 + t] = start + excl;
    if (b == NB - 1 && t == 0) rowptr[NNODES] = end;   // == NNZ
    __syncthreads();
    // pass 2: scatter to row-major packed (staged nt-read again)
    for (int idx = start + t; idx < end; idx += 1024) {
        v2i rec = __builtin_nontemporal_load((const v2i*)&staged[idx]);
        int rel = ((unsigned)rec.x) >> 19;
        int col = rec.x & 0x7FFFF;
        int pos = atomicAdd(&cur[rel], 1);
        int2 o; o.x = col; o.y = rec.y;
        packed[pos] = o;
    }
}

// ---------------- x0 -> bf16 ----------------

__global__ void k_init0(const float* __restrict__ ue, const float* __restrict__ ie,
                        unsigned short* __restrict__ xb0) {
    int i = blockIdx.x * blockDim.x + threadIdx.x;      // float4 index
    const int total = NNODES * DIM / 4;
    if (i >= total) return;
    const int userEnd = NUSERS * DIM / 4;
    float4 v;
    if (i < userEnd) {
        const float* s = (const float*)&((const float4*)ue)[i];
        v.x = __builtin_nontemporal_load(s + 0);
        v.y = __builtin_nontemporal_load(s + 1);
        v.z = __builtin_nontemporal_load(s + 2);
        v.w = __builtin_nontemporal_load(s + 3);
    } else {
        const float* s = (const float*)&((const float4*)ie)[i - userEnd];
        v.x = __builtin_nontemporal_load(s + 0);
        v.y = __builtin_nontemporal_load(s + 1);
        v.z = __builtin_nontemporal_load(s + 2);
        v.w = __builtin_nontemporal_load(s + 3);
    }
    ushort4 h;
    h.x = f32_to_bf16(v.x); h.y = f32_to_bf16(v.y);
    h.z = f32_to_bf16(v.z); h.w = f32_to_bf16(v.w);
    ((ushort4*)xb0)[i] = h;
}

// ---------------- CSR SpMM: one wave/row, SGPR records, nt streams ----------

// FINAL=0: y = bf16(s) via nt store        (layers 1,2)
// FINAL=1: out = (x0 + x1 + x2 + s)*0.25, all streams nt (loads + store);
// only the random gathers of xin are cached.
template <int FINAL>
__global__ void __launch_bounds__(256) k_spmm(
        const int* __restrict__ rowptr, const int2* __restrict__ packed,
        const unsigned short* __restrict__ xin,
        unsigned short* __restrict__ y,
        const unsigned short* __restrict__ xprev,
        const float* __restrict__ ue, const float* __restrict__ ie,
        float* __restrict__ out) {
    int row  = blockIdx.x * (blockDim.x >> 6) + (threadIdx.x >> 6);
    int lane = threadIdx.x & 63;
    if (row >= NNODES) return;
    int start = __builtin_amdgcn_readfirstlane(rowptr[row]);
    int end   = __builtin_amdgcn_readfirstlane(rowptr[row + 1]);
    const unsigned short* __restrict__ xl = xin + lane;
    float s0 = 0.f, s1 = 0.f, s2 = 0.f, s3 = 0.f;
    int idx = start;
    for (; idx + 4 <= end; idx += 4) {
        int2 e0 = packed[idx + 0];          // wave-uniform -> s_load
        int2 e1 = packed[idx + 1];
        int2 e2 = packed[idx + 2];
        int2 e3 = packed[idx + 3];
        float g0 = bf16_to_f32(xl[(size_t)e0.x << 6]);
        float g1 = bf16_to_f32(xl[(size_t)e1.x << 6]);
        float g2 = bf16_to_f32(xl[(size_t)e2.x << 6]);
        float g3 = bf16_to_f32(xl[(size_t)e3.x << 6]);
        s0 += __int_as_float(e0.y) * g0;
        s1 += __int_as_float(e1.y) * g1;
        s2 += __int_as_float(e2.y) * g2;
        s3 += __int_as_float(e3.y) * g3;
    }
    for (; idx < end; ++idx) {
        int2 e = packed[idx];
        s0 += __int_as_float(e.y) * bf16_to_f32(xl[(size_t)e.x << 6]);
    }
    float s = (s0 + s1) + (s2 + s3);
    size_t o = ((size_t)row << 6) + lane;
    if (FINAL) {
        float x0 = (row < NUSERS)
                   ? __builtin_nontemporal_load(&ue[o])
                   : __builtin_nontemporal_load(&ie[o - (size_t)NUSERS * DIM]);
        float x1 = bf16_to_f32(__builtin_nontemporal_load(&xprev[o]));
        float x2 = bf16_to_f32(__builtin_nontemporal_load(&xin[o]));
        __builtin_nontemporal_store((x0 + x1 + x2 + s) * 0.25f, &out[o]);
    } else {
        __builtin_nontemporal_store(f32_to_bf16(s), &y[o]);
    }
}

// ---------------- launch ----------------

extern "C" void kernel_launch(void* const* d_in, const int* in_sizes, int n_in,
                              void* d_out, int out_size, void* d_ws, size_t ws_size,
                              hipStream_t stream) {
    const float* ue   = (const float*)d_in[0];
    const float* ie   = (const float*)d_in[1];
    const int*   rows = (const int*)d_in[2];
    const int*   cols = (const int*)d_in[3];
    const float* vals = (const float*)d_in[4];
    float* out = (float*)d_out;

    const size_t embN = (size_t)NNODES * DIM;            // 19.2M elements
    char* p = (char*)d_ws;
    unsigned short* xb0 = (unsigned short*)p;  p += embN * 2;                 // 38.4 MB
    unsigned short* xb1 = (unsigned short*)p;  p += embN * 2;                 // 38.4 MB
    unsigned short* xb2 = (unsigned short*)p;  p += embN * 2;                 // 38.4 MB
    int*   rowptr = (int*)p;              p += (size_t)(NNODES + 16) * 4;     // 1.2 MB
    int*   bcnt   = (int*)p;              p += 512 * 4;
    int*   bbase  = (int*)p;              p += 512 * 4;
    int*   gcur   = (int*)p;              p += 512 * 4;
    int2*  staged = (int2*)p;             p += (size_t)NNZ_CNT * 8;           // 32 MB
    int2*  packed = (int2*)p;             p += (size_t)(NNZ_CNT + 16) * 8;    // 32 MB + pad

    const int row_blocks  = (NNODES + 3) / 4;             // 4 waves/block
    const int edge_hblocks = (NNZ_CNT + EPB - 1) / EPB;   // 489
    const int vec_blocks = (NNODES * DIM / 4 + 255) / 256;

    // --- bucket totals + bases ---
    hipMemsetAsync(bcnt, 0, 512 * 4, stream);
    hipMemsetAsync(packed + NNZ_CNT, 0, 16 * sizeof(int2), stream);  // tail pad
    k_bhist<<<edge_hblocks, 256, 0, stream>>>(rows, bcnt);
    k_bscan<<<1, 512, 0, stream>>>(bcnt, bbase, gcur);

    // --- bucket sort: COO -> staged (bucket-major) -> packed (row-major) ---
    k_bucketA<<<edge_hblocks, 256, 0, stream>>>(rows, cols, vals, gcur, staged);
    k_bucketB<<<NB, 1024, 0, stream>>>(bbase, staged, packed, rowptr);

    // --- x0 -> bf16 ---
    k_init0<<<vec_blocks, 256, 0, stream>>>(ue, ie, xb0);

    // --- 3 layers; mean fused into the last (reads x0 fp32 + x1,x2 bf16) ---
    k_spmm<0><<<row_blocks, 256, 0, stream>>>(rowptr, packed, xb0, xb1,
                                              (const unsigned short*)nullptr, ue, ie, (float*)nullptr);
    k_spmm<0><<<row_blocks, 256, 0, stream>>>(rowptr, packed, xb1, xb2,
                                              (const unsigned short*)nullptr, ue, ie, (float*)nullptr);
    k_spmm<1><<<row_blocks, 256, 0, stream>>>(rowptr, packed, xb2, (unsigned short*)nullptr,
                                              xb1, ue, ie, out);
}